// Round 1
// baseline (222.633 us; speedup 1.0000x reference)
//
#include <hip/hip_runtime.h>

#define LOG2E 1.4426950408889634f

typedef __bf16 bf16x8 __attribute__((ext_vector_type(8)));
typedef float f32x4 __attribute__((ext_vector_type(4)));

#define BB 2
#define NN 2048
#define CC 384
#define NH 12
#define HD 32
#define MROWS (BB * NN)   /* 4096 */
#define OCOLS (3 * CC)    /* 1152 */

__device__ __forceinline__ unsigned short f2bf(float f) {
  unsigned int u = __builtin_bit_cast(unsigned int, f);
  u += 0x7FFFu + ((u >> 16) & 1u);
  return (unsigned short)(u >> 16);
}

__device__ __forceinline__ bf16x8 ldg_bf8(const unsigned short* p) {
  uint4 v = *reinterpret_cast<const uint4*>(p);
  return __builtin_bit_cast(bf16x8, v);
}

// ---------------- prep: fp32->bf16 casts + bias/scale prefolds ----------------
__global__ __launch_bounds__(256) void prep_kernel(
    const float* __restrict__ x, const float* __restrict__ q_w,
    const float* __restrict__ kv_w, const float* __restrict__ proj_w,
    const float* __restrict__ pos_bias, const float* __restrict__ temperature,
    unsigned short* __restrict__ xb, unsigned short* __restrict__ qwb,
    unsigned short* __restrict__ kvwb, unsigned short* __restrict__ pwb,
    float* __restrict__ bias2, float* __restrict__ scales) {
  long i = (long)blockIdx.x * blockDim.x + threadIdx.x;
  const long NX = (long)MROWS * CC;   // 1572864
  const long NQW = CC * CC;           // 147456
  const long NKV = 2 * CC * CC;       // 294912
  const long NPW = CC * CC;           // 147456
  const long NBI = NH * NN;           // 24576
  if (i < NX) { xb[i] = f2bf(x[i]); return; }
  i -= NX;
  if (i < NQW) { qwb[i] = f2bf(q_w[i]); return; }
  i -= NQW;
  if (i < NKV) { kvwb[i] = f2bf(kv_w[i]); return; }
  i -= NKV;
  if (i < NPW) { pwb[i] = f2bf(proj_w[i]); return; }
  i -= NPW;
  if (i < NBI) { bias2[i] = pos_bias[i] * LOG2E; return; }
  i -= NBI;
  if (i < NH) {
    float t = temperature[i];
    // softplus(t) * ln(N) * log2(e) = softplus(t) * log2(2048) = softplus(t)*11
    scales[i] = log1pf(expf(t)) * 11.0f;
  }
}

// ---------------- GEMM: qkv_raw = x @ [q_w;kv_w]^T + bias ----------------
// 16x16x32 bf16 MFMA. Wave owns 16 rows x 64 cols; block = 4 waves = 64x64 tile.
__global__ __launch_bounds__(256) void gemm_qkv_kernel(
    const unsigned short* __restrict__ xb, const unsigned short* __restrict__ qwb,
    const unsigned short* __restrict__ kvwb, const float* __restrict__ q_b,
    const float* __restrict__ kv_b, float* __restrict__ qkv) {
  int wave = threadIdx.x >> 6;
  int lane = threadIdx.x & 63;
  int c = lane & 15, quad = lane >> 4;
  int m0 = blockIdx.x * 64 + wave * 16;
  int n0 = blockIdx.y * 64;
  const unsigned short* arow = xb + (long)(m0 + c) * CC + quad * 8;
  const unsigned short* brow[4];
#pragma unroll
  for (int t = 0; t < 4; ++t) {
    int o = n0 + t * 16 + c;
    brow[t] = (o < CC) ? (qwb + (long)o * CC + quad * 8)
                       : (kvwb + (long)(o - CC) * CC + quad * 8);
  }
  f32x4 acc[4] = {};
  for (int kk = 0; kk < CC; kk += 32) {
    bf16x8 a = ldg_bf8(arow + kk);
#pragma unroll
    for (int t = 0; t < 4; ++t) {
      bf16x8 b = ldg_bf8(brow[t] + kk);
      acc[t] = __builtin_amdgcn_mfma_f32_16x16x32_bf16(a, b, acc[t], 0, 0, 0);
    }
  }
#pragma unroll
  for (int t = 0; t < 4; ++t) {
    int o = n0 + t * 16 + c;
    float bv = (o < CC) ? q_b[o] : kv_b[o - CC];
#pragma unroll
    for (int r = 0; r < 4; ++r) {
      qkv[(long)(m0 + quad * 4 + r) * OCOLS + o] = acc[t][r] + bv;
    }
  }
}

// ---------------- norm: l2norm q,k; layout Q,K=(b,h,n,d), V^T=(b,h,d,n) bf16 --
__global__ __launch_bounds__(256) void norm_kernel(
    const float* __restrict__ qkv, const float* __restrict__ qe,
    const float* __restrict__ scales, unsigned short* __restrict__ Qs,
    unsigned short* __restrict__ Kn, unsigned short* __restrict__ VT) {
  int g = blockIdx.x * 8 + (threadIdx.x >> 5);  // (b*N+n)*NH + h
  int d = threadIdx.x & 31;
  int h = g % NH;
  int mn = g / NH;
  int b = mn / NN;
  int n = mn % NN;
  const float* rowp = qkv + (long)mn * OCOLS + h * HD + d;
  float qv = rowp[0];
  float kv = rowp[CC];
  float vv = rowp[2 * CC];
  float qs = qv * qv, ks = kv * kv;
#pragma unroll
  for (int off = 16; off; off >>= 1) {
    qs += __shfl_xor(qs, off, 32);
    ks += __shfl_xor(ks, off, 32);
  }
  float qn = qv / fmaxf(sqrtf(qs), 1e-12f);
  float knv = kv / fmaxf(sqrtf(ks), 1e-12f);
  float qout = (qn + qe[h * HD + d]) * scales[h];  // scale includes log2(e)
  long base = ((long)(b * NH + h) * NN + n) * HD + d;
  Qs[base] = f2bf(qout);
  Kn[base] = f2bf(knv);
  VT[((long)(b * NH + h) * HD + d) * NN + n] = f2bf(vv);
}

// ---------------- flash attention: per (b,h), 64 q-rows/block ----------------
__global__ __launch_bounds__(256) void attn_kernel(
    const unsigned short* __restrict__ Qs, const unsigned short* __restrict__ Kn,
    const unsigned short* __restrict__ VT, const float* __restrict__ bias2,
    unsigned short* __restrict__ ao) {
  __shared__ unsigned short Pbuf[4][16][72];  // per-wave P tile, +8 pad
  int wave = threadIdx.x >> 6;
  int lane = threadIdx.x & 63;
  int c = lane & 15, quad = lane >> 4;
  int pair = blockIdx.y;  // b*NH + h
  int h = pair % NH;
  int b = pair / NH;
  const unsigned short* Qp = Qs + (long)pair * NN * HD;
  const unsigned short* Kp = Kn + (long)pair * NN * HD;
  const unsigned short* Vp = VT + (long)pair * HD * NN;
  const float* bp = bias2 + h * NN;
  int q0 = blockIdx.x * 64 + wave * 16;
  bf16x8 qf = ldg_bf8(Qp + (long)(q0 + c) * HD + quad * 8);
  f32x4 o0 = {}, o1 = {};
  float m_r[4] = {-1e30f, -1e30f, -1e30f, -1e30f};
  float l_r[4] = {};
  unsigned short(*pb)[72] = Pbuf[wave];

  for (int k0 = 0; k0 < NN; k0 += 64) {
    f32x4 s[4];
#pragma unroll
    for (int t = 0; t < 4; ++t) {
      bf16x8 kf = ldg_bf8(Kp + (long)(k0 + t * 16 + c) * HD + quad * 8);
      f32x4 z = {};
      s[t] = __builtin_amdgcn_mfma_f32_16x16x32_bf16(qf, kf, z, 0, 0, 0);
      float bv = bp[k0 + t * 16 + c];  // logits already in log2 units
      s[t][0] += bv; s[t][1] += bv; s[t][2] += bv; s[t][3] += bv;
    }
#pragma unroll
    for (int r = 0; r < 4; ++r) {
      float v = fmaxf(fmaxf(s[0][r], s[1][r]), fmaxf(s[2][r], s[3][r]));
      v = fmaxf(v, __shfl_xor(v, 1, 16));
      v = fmaxf(v, __shfl_xor(v, 2, 16));
      v = fmaxf(v, __shfl_xor(v, 4, 16));
      v = fmaxf(v, __shfl_xor(v, 8, 16));
      float mnew = fmaxf(m_r[r], v);
      float alpha = exp2f(m_r[r] - mnew);
      m_r[r] = mnew;
      float rowsum = 0.f;
#pragma unroll
      for (int t = 0; t < 4; ++t) {
        float p = exp2f(s[t][r] - mnew);
        s[t][r] = p;
        rowsum += p;
      }
      rowsum += __shfl_xor(rowsum, 1, 16);
      rowsum += __shfl_xor(rowsum, 2, 16);
      rowsum += __shfl_xor(rowsum, 4, 16);
      rowsum += __shfl_xor(rowsum, 8, 16);
      l_r[r] = l_r[r] * alpha + rowsum;
      o0[r] *= alpha;
      o1[r] *= alpha;
#pragma unroll
      for (int t = 0; t < 4; ++t)
        pb[quad * 4 + r][t * 16 + c] = f2bf(s[t][r]);  // C-layout -> row-major
    }
    // PV: P (A-layout from LDS) x V^T rows (B-layout, contiguous 16B)
#pragma unroll
    for (int ch = 0; ch < 2; ++ch) {
      bf16x8 pf = __builtin_bit_cast(
          bf16x8, *reinterpret_cast<const uint4*>(&pb[c][ch * 32 + quad * 8]));
      bf16x8 v0 = ldg_bf8(Vp + (long)c * NN + k0 + ch * 32 + quad * 8);
      bf16x8 v1 = ldg_bf8(Vp + (long)(c + 16) * NN + k0 + ch * 32 + quad * 8);
      o0 = __builtin_amdgcn_mfma_f32_16x16x32_bf16(pf, v0, o0, 0, 0, 0);
      o1 = __builtin_amdgcn_mfma_f32_16x16x32_bf16(pf, v1, o1, 0, 0, 0);
    }
  }
#pragma unroll
  for (int r = 0; r < 4; ++r) {
    float inv = 1.0f / l_r[r];
    int q = q0 + quad * 4 + r;
    unsigned short* op = ao + (long)(b * NN + q) * CC + h * HD;
    op[c] = f2bf(o0[r] * inv);
    op[c + 16] = f2bf(o1[r] * inv);
  }
}

// ---------------- proj: out = attn_out @ proj_w^T + proj_b (fp32 out) --------
__global__ __launch_bounds__(256) void proj_kernel(
    const unsigned short* __restrict__ ab, const unsigned short* __restrict__ pwb,
    const float* __restrict__ proj_b, float* __restrict__ out) {
  int wave = threadIdx.x >> 6;
  int lane = threadIdx.x & 63;
  int c = lane & 15, quad = lane >> 4;
  int m0 = blockIdx.x * 64 + wave * 16;
  int n0 = blockIdx.y * 64;
  const unsigned short* arow = ab + (long)(m0 + c) * CC + quad * 8;
  f32x4 acc[4] = {};
  for (int kk = 0; kk < CC; kk += 32) {
    bf16x8 a = ldg_bf8(arow + kk);
#pragma unroll
    for (int t = 0; t < 4; ++t) {
      bf16x8 b = ldg_bf8(pwb + (long)(n0 + t * 16 + c) * CC + kk + quad * 8);
      acc[t] = __builtin_amdgcn_mfma_f32_16x16x32_bf16(a, b, acc[t], 0, 0, 0);
    }
  }
#pragma unroll
  for (int t = 0; t < 4; ++t) {
    int o = n0 + t * 16 + c;
    float bv = proj_b[o];
#pragma unroll
    for (int r = 0; r < 4; ++r) {
      out[(long)(m0 + quad * 4 + r) * CC + o] = acc[t][r] + bv;
    }
  }
}

extern "C" void kernel_launch(void* const* d_in, const int* in_sizes, int n_in,
                              void* d_out, int out_size, void* d_ws, size_t ws_size,
                              hipStream_t stream) {
  const float* x = (const float*)d_in[0];
  const float* q_w = (const float*)d_in[1];
  const float* q_b = (const float*)d_in[2];
  const float* kv_w = (const float*)d_in[3];
  const float* kv_b = (const float*)d_in[4];
  const float* qe = (const float*)d_in[5];
  const float* temp = (const float*)d_in[6];
  const float* pos_bias = (const float*)d_in[7];
  const float* proj_w = (const float*)d_in[8];
  const float* proj_b = (const float*)d_in[9];
  float* out = (float*)d_out;

  char* ws = (char*)d_ws;
  unsigned short* xb = (unsigned short*)(ws + 0);          // 3,145,728 B
  unsigned short* qwb = (unsigned short*)(ws + 3145728);   //   294,912 B
  unsigned short* kvwb = (unsigned short*)(ws + 3440640);  //   589,824 B
  unsigned short* pwb = (unsigned short*)(ws + 4030464);   //   294,912 B
  float* bias2 = (float*)(ws + 4325376);                   //    98,304 B
  float* scales = (float*)(ws + 4423680);                  //        48 B (pad 256)
  float* qkv = (float*)(ws + 4423936);                     // 18,874,368 B
  unsigned short* Qs = (unsigned short*)(ws + 23298304);   // 3,145,728 B
  unsigned short* Kn = (unsigned short*)(ws + 26444032);   // 3,145,728 B
  unsigned short* VT = (unsigned short*)(ws + 29589760);   // 3,145,728 B
  unsigned short* ao = (unsigned short*)(ws + 32735488);   // 3,145,728 B -> 35.9 MB total

  prep_kernel<<<8545, 256, 0, stream>>>(x, q_w, kv_w, proj_w, pos_bias, temp, xb,
                                        qwb, kvwb, pwb, bias2, scales);
  gemm_qkv_kernel<<<dim3(64, 18), 256, 0, stream>>>(xb, qwb, kvwb, q_b, kv_b, qkv);
  norm_kernel<<<6144, 256, 0, stream>>>(qkv, qe, scales, Qs, Kn, VT);
  attn_kernel<<<dim3(32, 24), 256, 0, stream>>>(Qs, Kn, VT, bias2, ao);
  proj_kernel<<<dim3(64, 6), 256, 0, stream>>>(ao, pwb, proj_b, out);
}

// Round 2
// 202.620 us; speedup vs baseline: 1.0988x; 1.0988x over previous
//
#include <hip/hip_runtime.h>

#define LOG2E 1.4426950408889634f

typedef __bf16 bf16x8 __attribute__((ext_vector_type(8)));
typedef float f32x4 __attribute__((ext_vector_type(4)));

#define BB 2
#define NN 2048
#define CC 384
#define NH 12
#define HD 32
#define MROWS (BB * NN)   /* 4096 */
#define OCOLS (3 * CC)    /* 1152 */

// native gfx950 f32->bf16 convert (v_cvt_pk_bf16_f32), RTNE
__device__ __forceinline__ unsigned short f2bf(float f) {
  __bf16 h = (__bf16)f;
  return __builtin_bit_cast(unsigned short, h);
}

__device__ __forceinline__ bf16x8 ldg_bf8(const unsigned short* p) {
  uint4 v = *reinterpret_cast<const uint4*>(p);
  return __builtin_bit_cast(bf16x8, v);
}

// ---------------- prep: fp32->bf16 casts + bias/scale prefolds ----------------
__global__ __launch_bounds__(256) void prep_kernel(
    const float* __restrict__ x, const float* __restrict__ q_w,
    const float* __restrict__ kv_w, const float* __restrict__ proj_w,
    const float* __restrict__ pos_bias, const float* __restrict__ temperature,
    unsigned short* __restrict__ xb, unsigned short* __restrict__ qwb,
    unsigned short* __restrict__ kvwb, unsigned short* __restrict__ pwb,
    float* __restrict__ bias2, float* __restrict__ scales) {
  long i = (long)blockIdx.x * blockDim.x + threadIdx.x;
  const long NX = (long)MROWS * CC;   // 1572864
  const long NQW = CC * CC;           // 147456
  const long NKV = 2 * CC * CC;       // 294912
  const long NPW = CC * CC;           // 147456
  const long NBI = NH * NN;           // 24576
  if (i < NX) { xb[i] = f2bf(x[i]); return; }
  i -= NX;
  if (i < NQW) { qwb[i] = f2bf(q_w[i]); return; }
  i -= NQW;
  if (i < NKV) { kvwb[i] = f2bf(kv_w[i]); return; }
  i -= NKV;
  if (i < NPW) { pwb[i] = f2bf(proj_w[i]); return; }
  i -= NPW;
  if (i < NBI) { bias2[i] = pos_bias[i] * LOG2E; return; }
  i -= NBI;
  if (i < NH) {
    float t = temperature[i];
    // softplus(t) * ln(N) * log2(e) = softplus(t) * log2(2048) = softplus(t)*11
    scales[i] = log1pf(expf(t)) * 11.0f;
  }
}

// ---------------- GEMM: qkv_raw = x @ [q_w;kv_w]^T + bias ----------------
// Wave owns 32 rows x 64 cols (2 A-frags, 8 acc); block = 4 waves = 128x64 tile.
__global__ __launch_bounds__(256) void gemm_qkv_kernel(
    const unsigned short* __restrict__ xb, const unsigned short* __restrict__ qwb,
    const unsigned short* __restrict__ kvwb, const float* __restrict__ q_b,
    const float* __restrict__ kv_b, float* __restrict__ qkv) {
  int wave = threadIdx.x >> 6;
  int lane = threadIdx.x & 63;
  int c = lane & 15, quad = lane >> 4;
  int m0 = blockIdx.x * 128 + wave * 32;
  int n0 = blockIdx.y * 64;
  const unsigned short* arow0 = xb + (long)(m0 + c) * CC + quad * 8;
  const unsigned short* arow1 = arow0 + 16 * CC;
  const unsigned short* brow[4];
#pragma unroll
  for (int t = 0; t < 4; ++t) {
    int o = n0 + t * 16 + c;
    brow[t] = (o < CC) ? (qwb + (long)o * CC + quad * 8)
                       : (kvwb + (long)(o - CC) * CC + quad * 8);
  }
  f32x4 acc0[4] = {}, acc1[4] = {};
  for (int kk = 0; kk < CC; kk += 32) {
    bf16x8 a0 = ldg_bf8(arow0 + kk);
    bf16x8 a1 = ldg_bf8(arow1 + kk);
#pragma unroll
    for (int t = 0; t < 4; ++t) {
      bf16x8 b = ldg_bf8(brow[t] + kk);
      acc0[t] = __builtin_amdgcn_mfma_f32_16x16x32_bf16(a0, b, acc0[t], 0, 0, 0);
      acc1[t] = __builtin_amdgcn_mfma_f32_16x16x32_bf16(a1, b, acc1[t], 0, 0, 0);
    }
  }
#pragma unroll
  for (int t = 0; t < 4; ++t) {
    int o = n0 + t * 16 + c;
    float bv = (o < CC) ? q_b[o] : kv_b[o - CC];
#pragma unroll
    for (int r = 0; r < 4; ++r) {
      qkv[(long)(m0 + quad * 4 + r) * OCOLS + o] = acc0[t][r] + bv;
      qkv[(long)(m0 + 16 + quad * 4 + r) * OCOLS + o] = acc1[t][r] + bv;
    }
  }
}

// ---------------- norm: l2norm q,k; layout Q,K=(b,h,n,d), V^T=(b,h,d,n) bf16 --
// Block owns one (b,h) x 64 n; V transposed through LDS for coalesced VT store.
__global__ __launch_bounds__(256) void norm_kernel(
    const float* __restrict__ qkv, const float* __restrict__ qe,
    const float* __restrict__ scales, unsigned short* __restrict__ Qs,
    unsigned short* __restrict__ Kn, unsigned short* __restrict__ VT) {
  __shared__ float vtf[64][33];
  int pair = blockIdx.y;  // b*NH + h
  int h = pair % NH;
  int b = pair / NH;
  int n0 = blockIdx.x * 64;
  int d = threadIdx.x & 31;
  int nl = threadIdx.x >> 5;  // 0..7
  float qeh = qe[h * HD + d];
  float sc = scales[h];
#pragma unroll
  for (int p = 0; p < 8; ++p) {
    int n = n0 + p * 8 + nl;
    const float* rowp = qkv + (long)(b * NN + n) * OCOLS + h * HD + d;
    float qv = rowp[0];
    float kv = rowp[CC];
    float vv = rowp[2 * CC];
    float qs = qv * qv, ks = kv * kv;
#pragma unroll
    for (int off = 16; off; off >>= 1) {
      qs += __shfl_xor(qs, off, 32);
      ks += __shfl_xor(ks, off, 32);
    }
    long base = ((long)pair * NN + n) * HD + d;
    Qs[base] = f2bf((qv / fmaxf(sqrtf(qs), 1e-12f) + qeh) * sc);
    Kn[base] = f2bf(kv / fmaxf(sqrtf(ks), 1e-12f));
    vtf[p * 8 + nl][d] = vv;
  }
  __syncthreads();
  int lane = threadIdx.x & 63;
  int w = threadIdx.x >> 6;
#pragma unroll
  for (int i = 0; i < 8; ++i) {
    int dr = w * 8 + i;
    VT[((long)pair * HD + dr) * NN + n0 + lane] = f2bf(vtf[lane][dr]);
  }
}

// ---------------- flash attention, NO online max (logits bounded ~+-47) ------
__global__ __launch_bounds__(256) void attn_kernel(
    const unsigned short* __restrict__ Qs, const unsigned short* __restrict__ Kn,
    const unsigned short* __restrict__ VT, const float* __restrict__ bias2,
    unsigned short* __restrict__ ao) {
  __shared__ unsigned short Pbuf[4][16][72];  // per-wave P tile, +8 pad
  int wave = threadIdx.x >> 6;
  int lane = threadIdx.x & 63;
  int c = lane & 15, quad = lane >> 4;
  int pair = blockIdx.y;  // b*NH + h
  int h = pair % NH;
  int b = pair / NH;
  const unsigned short* Qp = Qs + (long)pair * NN * HD;
  const unsigned short* Kp = Kn + (long)pair * NN * HD;
  const unsigned short* Vp = VT + (long)pair * HD * NN;
  const float* bp = bias2 + h * NN;
  int q0 = blockIdx.x * 64 + wave * 16;
  bf16x8 qf = ldg_bf8(Qp + (long)(q0 + c) * HD + quad * 8);
  f32x4 o0 = {}, o1 = {};
  float rs[4] = {};
  unsigned short(*pb)[72] = Pbuf[wave];

  for (int k0 = 0; k0 < NN; k0 += 64) {
    f32x4 s[4];
    float bv[4];
#pragma unroll
    for (int t = 0; t < 4; ++t) {
      bf16x8 kf = ldg_bf8(Kp + (long)(k0 + t * 16 + c) * HD + quad * 8);
      f32x4 z = {};
      s[t] = __builtin_amdgcn_mfma_f32_16x16x32_bf16(qf, kf, z, 0, 0, 0);
      bv[t] = bp[k0 + t * 16 + c];  // log2-unit bias
    }
#pragma unroll
    for (int r = 0; r < 4; ++r) {
      float p0 = exp2f(s[0][r] + bv[0]);
      float p1 = exp2f(s[1][r] + bv[1]);
      float p2 = exp2f(s[2][r] + bv[2]);
      float p3 = exp2f(s[3][r] + bv[3]);
      rs[r] += (p0 + p1) + (p2 + p3);
      int row = quad * 4 + r;
      pb[row][c] = f2bf(p0);
      pb[row][16 + c] = f2bf(p1);
      pb[row][32 + c] = f2bf(p2);
      pb[row][48 + c] = f2bf(p3);
    }
    // PV: P (A-layout from LDS) x V^T rows (B-layout, contiguous 16B)
#pragma unroll
    for (int ch = 0; ch < 2; ++ch) {
      bf16x8 pf = __builtin_bit_cast(
          bf16x8, *reinterpret_cast<const uint4*>(&pb[c][ch * 32 + quad * 8]));
      bf16x8 v0 = ldg_bf8(Vp + (long)c * NN + k0 + ch * 32 + quad * 8);
      bf16x8 v1 = ldg_bf8(Vp + (long)(c + 16) * NN + k0 + ch * 32 + quad * 8);
      o0 = __builtin_amdgcn_mfma_f32_16x16x32_bf16(pf, v0, o0, 0, 0, 0);
      o1 = __builtin_amdgcn_mfma_f32_16x16x32_bf16(pf, v1, o1, 0, 0, 0);
    }
  }
#pragma unroll
  for (int r = 0; r < 4; ++r) {
    float l = rs[r];
    l += __shfl_xor(l, 1, 16);
    l += __shfl_xor(l, 2, 16);
    l += __shfl_xor(l, 4, 16);
    l += __shfl_xor(l, 8, 16);
    float inv = 1.0f / l;
    int q = q0 + quad * 4 + r;
    unsigned short* op = ao + (long)(b * NN + q) * CC + h * HD;
    op[c] = f2bf(o0[r] * inv);
    op[c + 16] = f2bf(o1[r] * inv);
  }
}

// ---------------- proj: out = attn_out @ proj_w^T + proj_b (fp32 out) --------
__global__ __launch_bounds__(256) void proj_kernel(
    const unsigned short* __restrict__ ab, const unsigned short* __restrict__ pwb,
    const float* __restrict__ proj_b, float* __restrict__ out) {
  int wave = threadIdx.x >> 6;
  int lane = threadIdx.x & 63;
  int c = lane & 15, quad = lane >> 4;
  int m0 = blockIdx.x * 64 + wave * 16;
  int n0 = blockIdx.y * 64;
  const unsigned short* arow = ab + (long)(m0 + c) * CC + quad * 8;
  f32x4 acc[4] = {};
  for (int kk = 0; kk < CC; kk += 32) {
    bf16x8 a = ldg_bf8(arow + kk);
#pragma unroll
    for (int t = 0; t < 4; ++t) {
      bf16x8 b = ldg_bf8(pwb + (long)(n0 + t * 16 + c) * CC + kk + quad * 8);
      acc[t] = __builtin_amdgcn_mfma_f32_16x16x32_bf16(a, b, acc[t], 0, 0, 0);
    }
  }
#pragma unroll
  for (int t = 0; t < 4; ++t) {
    int o = n0 + t * 16 + c;
    float bv = proj_b[o];
#pragma unroll
    for (int r = 0; r < 4; ++r) {
      out[(long)(m0 + quad * 4 + r) * CC + o] = acc[t][r] + bv;
    }
  }
}

extern "C" void kernel_launch(void* const* d_in, const int* in_sizes, int n_in,
                              void* d_out, int out_size, void* d_ws, size_t ws_size,
                              hipStream_t stream) {
  const float* x = (const float*)d_in[0];
  const float* q_w = (const float*)d_in[1];
  const float* q_b = (const float*)d_in[2];
  const float* kv_w = (const float*)d_in[3];
  const float* kv_b = (const float*)d_in[4];
  const float* qe = (const float*)d_in[5];
  const float* temp = (const float*)d_in[6];
  const float* pos_bias = (const float*)d_in[7];
  const float* proj_w = (const float*)d_in[8];
  const float* proj_b = (const float*)d_in[9];
  float* out = (float*)d_out;

  char* ws = (char*)d_ws;
  unsigned short* xb = (unsigned short*)(ws + 0);          // 3,145,728 B
  unsigned short* qwb = (unsigned short*)(ws + 3145728);   //   294,912 B
  unsigned short* kvwb = (unsigned short*)(ws + 3440640);  //   589,824 B
  unsigned short* pwb = (unsigned short*)(ws + 4030464);   //   294,912 B
  float* bias2 = (float*)(ws + 4325376);                   //    98,304 B
  float* scales = (float*)(ws + 4423680);                  //        48 B (pad 256)
  float* qkv = (float*)(ws + 4423936);                     // 18,874,368 B
  unsigned short* Qs = (unsigned short*)(ws + 23298304);   // 3,145,728 B
  unsigned short* Kn = (unsigned short*)(ws + 26444032);   // 3,145,728 B
  unsigned short* VT = (unsigned short*)(ws + 29589760);   // 3,145,728 B
  unsigned short* ao = (unsigned short*)(ws + 32735488);   // 3,145,728 B -> 35.9 MB total

  prep_kernel<<<8545, 256, 0, stream>>>(x, q_w, kv_w, proj_w, pos_bias, temp, xb,
                                        qwb, kvwb, pwb, bias2, scales);
  gemm_qkv_kernel<<<dim3(32, 18), 256, 0, stream>>>(xb, qwb, kvwb, q_b, kv_b, qkv);
  norm_kernel<<<dim3(32, 24), 256, 0, stream>>>(qkv, qe, scales, Qs, Kn, VT);
  attn_kernel<<<dim3(32, 24), 256, 0, stream>>>(Qs, Kn, VT, bias2, ao);
  proj_kernel<<<dim3(64, 6), 256, 0, stream>>>(ao, pwb, proj_b, out);
}